// Round 7
// baseline (216.257 us; speedup 1.0000x reference)
//
#include <hip/hip_runtime.h>
#include <stdint.h>

static constexpr int B = 32, S = 2048, F = 768;
static constexpr int SC = 64;            // rows per delta block
static constexpr int NSC = S / SC;       // 32 sub-chunks per batch
static constexpr int F4 = F / 4;         // 192 (row stride in float4/int4)
static constexpr int FT = F4;            // 192 threads, 4 features each

typedef float v4f __attribute__((ext_vector_type(4)));   // native vector for nt builtins

__device__ __forceinline__ v4f mk4(float a, float b, float c, float d) {
    v4f v; v.x = a; v.y = b; v.z = c; v.w = d; return v;
}

// One dispatch: even blocks compute fwd+bwd deltas for chunk pair=blk/2,
// odd blocks do the flipped-X copy for the same chunk. Copy waves (cheap,
// pure streaming) co-reside with delta waves and keep HBM saturated while
// delta waves sit in probe/carry latency. All output stores nontemporal.
__global__ __launch_bounds__(FT) void fusedK(const float* __restrict__ ts,
                                             const v4f* __restrict__ x,
                                             const int4* __restrict__ masks,
                                             float* __restrict__ out) {
    const int blk = blockIdx.x;
    const int pair = blk >> 1;               // 0..1023 : (b, sc)
    const int b  = pair >> 5;                // / NSC
    const int sc = pair & (NSC - 1);
    const int g0 = sc * SC;
    const int j  = threadIdx.x;
    const size_t N4 = (size_t)B * S * F4;    // plane size in float4

    if (blk & 1) {
        // ---------------- flip-copy block: o2[b, g0+k, :] = x[b, S-1-(g0+k), :]
        const v4f* xb = x + (size_t)b * S * F4 + j;
        v4f* o2 = reinterpret_cast<v4f*>(out) + 2 * N4 + (size_t)(b * S + g0) * F4 + j;
        #pragma unroll 8
        for (int k = 0; k < SC; ++k) {
            __builtin_nontemporal_store(
                __builtin_nontemporal_load(&xb[(size_t)(S - 1 - g0 - k) * F4]),
                &o2[(size_t)k * F4]);
        }
        return;
    }

    // ---------------- delta block ----------------
    const float* tsb = ts + (size_t)b * S;
    const int4* mbase = masks + (size_t)b * S * F4 + j;

    __shared__ float tss[SC];
    if (j < SC) tss[j] = tsb[g0 + j];
    __syncthreads();

    // ---- Phase 1: bulk-collect own 64 mask rows into bit-words (8 independent loads/group)
    uint32_t a0 = 0, a1 = 0, a2 = 0, a3 = 0;   // rows g0..g0+31
    uint32_t c0 = 0, c1 = 0, c2 = 0, c3 = 0;   // rows g0+32..g0+63
    #pragma unroll
    for (int g = 0; g < 8; ++g) {
        int4 mv[8];
        #pragma unroll
        for (int q = 0; q < 8; ++q) mv[q] = mbase[(size_t)(g0 + g * 8 + q) * F4];
        #pragma unroll
        for (int q = 0; q < 8; ++q) {
            const int k = g * 8 + q;
            const uint32_t bit = 1u << (k & 31);
            if (k < 32) {
                if (mv[q].x) a0 |= bit;
                if (mv[q].y) a1 |= bit;
                if (mv[q].z) a2 |= bit;
                if (mv[q].w) a3 |= bit;
            } else {
                if (mv[q].x) c0 |= bit;
                if (mv[q].y) c1 |= bit;
                if (mv[q].z) c2 |= bit;
                if (mv[q].w) c3 |= bit;
            }
        }
    }

    // ---- Phase 2: forward carry probe (last obs ts at row < g0; virtual at 0)
    float t0v = tsb[0];
    float p0 = t0v, p1 = t0v, p2 = t0v, p3 = t0v;
    if (g0 > 0) {
        unsigned um = 0xFu;
        int r = g0 - 1;
        while (um && r >= 0) {
            int rl = (r - 7 > 0) ? r - 7 : 0;
            int nn = r - rl + 1;
            int4 mv[8];
            #pragma unroll
            for (int q = 0; q < 8; ++q) if (q < nn) mv[q] = mbase[(size_t)(r - q) * F4];
            #pragma unroll
            for (int q = 0; q < 8; ++q) if (q < nn) {
                float t = tsb[r - q];
                if ((um & 1u) && mv[q].x) { p0 = t; um &= ~1u; }
                if ((um & 2u) && mv[q].y) { p1 = t; um &= ~2u; }
                if ((um & 4u) && mv[q].z) { p2 = t; um &= ~4u; }
                if ((um & 8u) && mv[q].w) { p3 = t; um &= ~8u; }
            }
            r = rl - 1;
        }
    }

    // ---- Phase 3: backward carry probe (first obs ts at row >= g0+SC; virtual at S-1)
    float tev = tsb[S - 1];
    float n0 = tev, n1 = tev, n2 = tev, n3 = tev;
    if (g0 + SC < S) {
        unsigned um = 0xFu;
        int r = g0 + SC;
        while (um && r < S) {
            int rh = (r + 7 < S - 1) ? r + 7 : S - 1;
            int nn = rh - r + 1;
            int4 mv[8];
            #pragma unroll
            for (int q = 0; q < 8; ++q) if (q < nn) mv[q] = mbase[(size_t)(r + q) * F4];
            #pragma unroll
            for (int q = 0; q < 8; ++q) if (q < nn) {
                float t = tsb[r + q];
                if ((um & 1u) && mv[q].x) { n0 = t; um &= ~1u; }
                if ((um & 2u) && mv[q].y) { n1 = t; um &= ~2u; }
                if ((um & 4u) && mv[q].z) { n2 = t; um &= ~4u; }
                if ((um & 8u) && mv[q].w) { n3 = t; um &= ~8u; }
            }
            r = rh + 1;
        }
    }

    // ---- Phase 4: forward-delta stores (nontemporal, bit-driven carries)
    v4f* o0 = reinterpret_cast<v4f*>(out) + (size_t)(b * S + g0) * F4 + j;
    #pragma unroll
    for (int k = 0; k < 32; ++k) {
        float t = tss[k];
        __builtin_nontemporal_store(mk4(t - p0, t - p1, t - p2, t - p3), &o0[(size_t)k * F4]);
        const uint32_t bit = 1u << k;
        if (a0 & bit) p0 = t;
        if (a1 & bit) p1 = t;
        if (a2 & bit) p2 = t;
        if (a3 & bit) p3 = t;
    }
    #pragma unroll
    for (int k = 32; k < 64; ++k) {
        float t = tss[k];
        __builtin_nontemporal_store(mk4(t - p0, t - p1, t - p2, t - p3), &o0[(size_t)k * F4]);
        const uint32_t bit = 1u << (k - 32);
        if (c0 & bit) p0 = t;
        if (c1 & bit) p1 = t;
        if (c2 & bit) p2 = t;
        if (c3 & bit) p3 = t;
    }

    // ---- Phase 5: backward-delta stores, FLIPPED coords:
    //      out1[b, S-1-(g0+k), :] = ts[first obs > g0+k] - ts[g0+k]
    v4f* o1b = reinterpret_cast<v4f*>(out) + N4 + (size_t)b * S * F4 + j;
    #pragma unroll
    for (int k = 63; k >= 32; --k) {
        float t = tss[k];
        size_t fr = (size_t)(S - 1 - g0 - k) * F4;
        __builtin_nontemporal_store(mk4(n0 - t, n1 - t, n2 - t, n3 - t), &o1b[fr]);
        const uint32_t bit = 1u << (k - 32);
        if (c0 & bit) n0 = t;
        if (c1 & bit) n1 = t;
        if (c2 & bit) n2 = t;
        if (c3 & bit) n3 = t;
    }
    #pragma unroll
    for (int k = 31; k >= 0; --k) {
        float t = tss[k];
        size_t fr = (size_t)(S - 1 - g0 - k) * F4;
        __builtin_nontemporal_store(mk4(n0 - t, n1 - t, n2 - t, n3 - t), &o1b[fr]);
        const uint32_t bit = 1u << k;
        if (a0 & bit) n0 = t;
        if (a1 & bit) n1 = t;
        if (a2 & bit) n2 = t;
        if (a3 & bit) n3 = t;
    }
}

extern "C" void kernel_launch(void* const* d_in, const int* in_sizes, int n_in,
                              void* d_out, int out_size, void* d_ws, size_t ws_size,
                              hipStream_t stream) {
    const float* ts    = (const float*)d_in[0];
    const v4f* x       = (const v4f*)d_in[1];
    const int4*  masks = (const int4*)d_in[2];
    float* out = (float*)d_out;
    fusedK<<<2 * B * NSC, FT, 0, stream>>>(ts, x, masks, out);
}